// Round 5
// baseline (238.894 us; speedup 1.0000x reference)
//
#include <hip/hip_runtime.h>

// TripletColbertLoss on MFMA: q (B,Q,D), p/n (B,K,D) fp32 -> scalar.
// loss = relu(0.2 + neg - pos), score = sum_{b,q} max_k q.d
// B=256 Q=256 K=512 D=128.
//
// R5: intra-wave software pipeline. R4 post-mortem showed pipes SERIALIZED
// (phase = MFMA + LDS + VALU, not max): every wave ran convert->write->
// barrier->mfma as a serial chain and co-resident blocks convoyed. Fix:
// fuse tile t+1's convert/LDS-write and tile t+2's global loads INTO the
// MFMA loop over tile t, so each wave's stream mixes VALU/LDS/MFMA.
// Also: 6 independent per-term accumulators (same-acc MFMA distance 6 insts)
// and v_perm_b32 bf16 packing (conversion VALU -40%).
// Grid (batch, pass, q-half) = 1024 blocks = 4 blocks/CU.

#define MARGIN   0.2f
#define Bn       256
#define Qn       256
#define Kn       512
#define Dn       128
#define TN       32            // docs per tile
#define NT       (Kn / TN)     // 16 tiles
#define BSTR     136           // doc stride (bf16 units): 272 B, 16B-aligned, bank offset 4
#define NTHREADS 256
#define MI       2             // 16-row MFMA tiles per wave (32 q rows)

typedef __attribute__((ext_vector_type(8))) short short8;
typedef __attribute__((ext_vector_type(4))) float f32x4;

// pack_hi(a,b): low16 = hi16(a), high16 = hi16(b) -> bf16x2 in memory order
__device__ __forceinline__ unsigned int pack_hi_bits(unsigned int ua, unsigned int ub) {
    return __builtin_amdgcn_perm(ub, ua, 0x07060302);
}

// Convert float4 (4 dims of one doc) -> hi/lo bf16 planes, one b64 write each.
// Truncation split: x = hi + lo; hi = trunc16(x), lo = trunc16(x - hi).
__device__ __forceinline__ void stage_chunk(short* __restrict__ hiP,
                                            short* __restrict__ loP,
                                            int doc, int d4, float4 v) {
    unsigned ux = __float_as_uint(v.x), uy = __float_as_uint(v.y);
    unsigned uz = __float_as_uint(v.z), uw = __float_as_uint(v.w);
    float lx = v.x - __uint_as_float(ux & 0xFFFF0000u);
    float ly = v.y - __uint_as_float(uy & 0xFFFF0000u);
    float lz = v.z - __uint_as_float(uz & 0xFFFF0000u);
    float lw = v.w - __uint_as_float(uw & 0xFFFF0000u);
    uint2 hi, lo;
    hi.x = pack_hi_bits(ux, uy);
    hi.y = pack_hi_bits(uz, uw);
    lo.x = pack_hi_bits(__float_as_uint(lx), __float_as_uint(ly));
    lo.y = pack_hi_bits(__float_as_uint(lz), __float_as_uint(lw));
    *(uint2*)&hiP[doc * BSTR + d4 * 4] = hi;
    *(uint2*)&loP[doc * BSTR + d4 * 4] = lo;
}

// Convert 8 consecutive floats -> short8 hi/lo fragments (A-side, once).
__device__ __forceinline__ void cvt8(const float* __restrict__ src,
                                     short8& hi, short8& lo) {
    float4 v0 = *(const float4*)src;
    float4 v1 = *(const float4*)(src + 4);
    float x[8] = {v0.x, v0.y, v0.z, v0.w, v1.x, v1.y, v1.z, v1.w};
    union { unsigned u[4]; short8 s; } H, L;
#pragma unroll
    for (int k = 0; k < 4; ++k) {
        unsigned u0 = __float_as_uint(x[2 * k]);
        unsigned u1 = __float_as_uint(x[2 * k + 1]);
        float l0 = x[2 * k]     - __uint_as_float(u0 & 0xFFFF0000u);
        float l1 = x[2 * k + 1] - __uint_as_float(u1 & 0xFFFF0000u);
        H.u[k] = pack_hi_bits(u0, u1);
        L.u[k] = pack_hi_bits(__float_as_uint(l0), __float_as_uint(l1));
    }
    hi = H.s; lo = L.s;
}

__global__ __launch_bounds__(NTHREADS, 4)
void colbert_pipe_kernel(const float* __restrict__ qg,
                         const float* __restrict__ pg,
                         const float* __restrict__ ng,
                         double* __restrict__ sum_ws) {
    __shared__ short Bs[2][2][TN * BSTR];   // [buf][hi/lo][doc*BSTR + dim] 34816 B
    __shared__ float part[4];

    const int tid  = threadIdx.x;
    const int w    = tid >> 6;
    const int lane = tid & 63;
    const int l16  = lane & 15;
    const int quad = lane >> 4;
    const int b    = blockIdx.x;
    const int pass = blockIdx.y;            // 0 -> p (+), 1 -> n (-)
    const int qh   = blockIdx.z;            // q-half: rows qh*128 .. +127

    const float* docb = (pass ? ng : pg) + (size_t)b * Kn * Dn;
    const int   d4    = tid & 31;           // doc-dim chunk this thread stages

    // Prefetch tile 0 first (loads in flight during A conversion).
    float4 pre[4];
    {
        const float4* s4 = (const float4*)docb;
#pragma unroll
        for (int k = 0; k < 4; ++k) pre[k] = s4[tid + 256 * k];
    }

    // A fragments: 32 q-rows per wave, hi/lo bf16 (64 VGPR).
    // 16x16x32 A layout: lane holds A[m = l16][k = quad*8 + j].
    short8 Ahi[MI][4], Alo[MI][4];
    {
        const float* qb = qg + ((size_t)b * Qn + qh * 128) * Dn;
#pragma unroll
        for (int mi = 0; mi < MI; ++mi)
#pragma unroll
            for (int ks = 0; ks < 4; ++ks)
                cvt8(qb + (size_t)(w * 32 + mi * 16 + l16) * Dn + ks * 32 + quad * 8,
                     Ahi[mi][ks], Alo[mi][ks]);
    }

    float maxv[MI][4];
#pragma unroll
    for (int mi = 0; mi < MI; ++mi)
#pragma unroll
        for (int r = 0; r < 4; ++r) maxv[mi][r] = -3e38f;

    // Prologue: stage tile 0 into buf 0, then prefetch tile 1.
    {
#pragma unroll
        for (int k = 0; k < 4; ++k) {
            int doc = (tid + 256 * k) >> 5;
            stage_chunk(&Bs[0][0][0], &Bs[0][1][0], doc, d4, pre[k]);
        }
        const float4* s4 = (const float4*)(docb + (size_t)TN * Dn);
#pragma unroll
        for (int k = 0; k < 4; ++k) pre[k] = s4[tid + 256 * k];
    }
    __syncthreads();

    for (int t = 0; t < NT; ++t) {
        const int cur = t & 1, nxt = cur ^ 1;
        const int tload = (t + 2 < NT) ? t + 2 : NT - 1;   // clamped (harmless refetch)
        const float4* s4n = (const float4*)(docb + (size_t)tload * TN * Dn);

#pragma unroll
        for (int ni = 0; ni < 2; ++ni) {
            f32x4 a0[MI], a1[MI], a2[MI];   // per-term accumulators
#pragma unroll
            for (int mi = 0; mi < MI; ++mi) {
                a0[mi] = (f32x4){0.f, 0.f, 0.f, 0.f};
                a1[mi] = (f32x4){0.f, 0.f, 0.f, 0.f};
                a2[mi] = (f32x4){0.f, 0.f, 0.f, 0.f};
            }
#pragma unroll
            for (int ks = 0; ks < 4; ++ks) {
                const int off = (ni * 16 + l16) * BSTR + ks * 32 + quad * 8;
                short8 bhi = *(const short8*)&Bs[cur][0][off];
                short8 blo = *(const short8*)&Bs[cur][1][off];

                // ---- interleaved staging for the next tiles (hides under MFMA)
                const int it = ni * 4 + ks;
                if (it < 4) {
                    if (t + 1 < NT) {
                        int doc = (tid + 256 * it) >> 5;
                        stage_chunk(&Bs[nxt][0][0], &Bs[nxt][1][0], doc, d4, pre[it]);
                    }
                } else {
                    pre[it - 4] = s4n[tid + 256 * (it - 4)];
                }

                // ---- MFMAs: same-acc reuse distance = 6 instructions
#pragma unroll
                for (int mi = 0; mi < MI; ++mi)
                    a0[mi] = __builtin_amdgcn_mfma_f32_16x16x32_bf16(
                        Ahi[mi][ks], bhi, a0[mi], 0, 0, 0);
#pragma unroll
                for (int mi = 0; mi < MI; ++mi)
                    a1[mi] = __builtin_amdgcn_mfma_f32_16x16x32_bf16(
                        Alo[mi][ks], bhi, a1[mi], 0, 0, 0);
#pragma unroll
                for (int mi = 0; mi < MI; ++mi)
                    a2[mi] = __builtin_amdgcn_mfma_f32_16x16x32_bf16(
                        Ahi[mi][ks], blo, a2[mi], 0, 0, 0);
            }
            // combine terms + running row-max (C/D: col=l16, row=quad*4+r)
#pragma unroll
            for (int mi = 0; mi < MI; ++mi)
#pragma unroll
                for (int r = 0; r < 4; ++r) {
                    float s = a0[mi][r] + a1[mi][r] + a2[mi][r];
                    maxv[mi][r] = fmaxf(maxv[mi][r], s);
                }
        }
        __syncthreads();
    }

    // max over the 16 doc-column lanes
#pragma unroll
    for (int off = 1; off < 16; off <<= 1)
#pragma unroll
        for (int mi = 0; mi < MI; ++mi)
#pragma unroll
            for (int r = 0; r < 4; ++r)
                maxv[mi][r] = fmaxf(maxv[mi][r], __shfl_xor(maxv[mi][r], off));

    float s = 0.f;
#pragma unroll
    for (int mi = 0; mi < MI; ++mi)
#pragma unroll
        for (int r = 0; r < 4; ++r) s += maxv[mi][r];
    if (l16 != 0) s = 0.f;                  // one copy per quad
    s += __shfl_xor(s, 16);
    s += __shfl_xor(s, 32);
    if (lane == 0) part[w] = s;
    __syncthreads();
    if (tid == 0) {
        double t = (double)part[0] + part[1] + part[2] + part[3];
        atomicAdd(sum_ws, pass ? -t : t);   // S = pos - neg, exact in fp64
    }
}

__global__ void finalize_kernel(const double* __restrict__ sum_ws,
                                float* __restrict__ out) {
    out[0] = fmaxf(0.0f, MARGIN - (float)sum_ws[0]);
}

extern "C" void kernel_launch(void* const* d_in, const int* in_sizes, int n_in,
                              void* d_out, int out_size, void* d_ws, size_t ws_size,
                              hipStream_t stream) {
    const float* q = (const float*)d_in[0];
    const float* p = (const float*)d_in[1];
    const float* n = (const float*)d_in[2];
    float* out = (float*)d_out;
    double* ws = (double*)d_ws;

    hipMemsetAsync(ws, 0, sizeof(double), stream);  // ws re-poisoned each call

    colbert_pipe_kernel<<<dim3(Bn, 2, 2), NTHREADS, 0, stream>>>(q, p, n, ws);
    finalize_kernel<<<1, 1, 0, stream>>>(ws, out);
}

// Round 6
// 183.672 us; speedup vs baseline: 1.3007x; 1.3007x over previous
//
#include <hip/hip_runtime.h>

// TripletColbertLoss on MFMA: q (B,Q,D), p/n (B,K,D) fp32 -> scalar.
// loss = relu(0.2 + neg - pos), score = sum_{b,q} max_k q.d
// B=256 Q=256 K=512 D=128.
//
// R6: 32x32x16 MFMA (2x FLOP per LDS B-read vs 16x16x32, 15% faster pipe),
// NO q-split: block = (batch, pass), 4 waves x 64 q-rows = all 256 q.
// Grid (256,2) = 512 blocks = 2/CU; launch_bounds(256,2) -> ~236 VGPR fits
// without spills (R5 died of scratch spills under a 128 cap).
// bf16 truncation hi/lo split, 3 terms: Ahi*Bhi + Alo*Bhi + Ahi*Blo.
// R4-proven skeleton: stage -> barrier -> prefetch -> MFMA, double buffer.
// Per-block signed partial -> one fp64 atomicAdd (exact).

#define MARGIN   0.2f
#define Bn       256
#define Qn       256
#define Kn       512
#define Dn       128
#define TN       32            // docs per tile
#define NT       (Kn / TN)     // 16 tiles
#define BSTR     136           // doc stride (bf16 units): 272 B, 16B-aligned
#define NTHREADS 256
#define MI       2             // 32-row MFMA tiles per wave (64 q rows)

typedef __attribute__((ext_vector_type(8)))  short short8;
typedef __attribute__((ext_vector_type(16))) float f32x16;

// pack_hi(a,b): low16 = hi16(a), high16 = hi16(b) -> bf16x2 in memory order
__device__ __forceinline__ unsigned int pack_hi_bits(unsigned int ua, unsigned int ub) {
    return __builtin_amdgcn_perm(ub, ua, 0x07060302);
}

// float4 (4 dims of one doc) -> hi/lo bf16 planes, one b64 write each.
// Truncation split: x = hi + lo; hi = trunc16(x), lo = trunc16(x - hi).
__device__ __forceinline__ void stage_chunk(short* __restrict__ hiP,
                                            short* __restrict__ loP,
                                            int doc, int d4, float4 v) {
    unsigned ux = __float_as_uint(v.x), uy = __float_as_uint(v.y);
    unsigned uz = __float_as_uint(v.z), uw = __float_as_uint(v.w);
    float lx = v.x - __uint_as_float(ux & 0xFFFF0000u);
    float ly = v.y - __uint_as_float(uy & 0xFFFF0000u);
    float lz = v.z - __uint_as_float(uz & 0xFFFF0000u);
    float lw = v.w - __uint_as_float(uw & 0xFFFF0000u);
    uint2 hi, lo;
    hi.x = pack_hi_bits(ux, uy);
    hi.y = pack_hi_bits(uz, uw);
    lo.x = pack_hi_bits(__float_as_uint(lx), __float_as_uint(ly));
    lo.y = pack_hi_bits(__float_as_uint(lz), __float_as_uint(lw));
    *(uint2*)&hiP[doc * BSTR + d4 * 4] = hi;
    *(uint2*)&loP[doc * BSTR + d4 * 4] = lo;
}

// 8 consecutive floats -> short8 hi/lo fragments (A-side, loaded once).
__device__ __forceinline__ void cvt8(const float* __restrict__ src,
                                     short8& hi, short8& lo) {
    float4 v0 = *(const float4*)src;
    float4 v1 = *(const float4*)(src + 4);
    float x[8] = {v0.x, v0.y, v0.z, v0.w, v1.x, v1.y, v1.z, v1.w};
    union { unsigned u[4]; short8 s; } H, L;
#pragma unroll
    for (int k = 0; k < 4; ++k) {
        unsigned u0 = __float_as_uint(x[2 * k]);
        unsigned u1 = __float_as_uint(x[2 * k + 1]);
        float l0 = x[2 * k]     - __uint_as_float(u0 & 0xFFFF0000u);
        float l1 = x[2 * k + 1] - __uint_as_float(u1 & 0xFFFF0000u);
        H.u[k] = pack_hi_bits(u0, u1);
        L.u[k] = pack_hi_bits(__float_as_uint(l0), __float_as_uint(l1));
    }
    hi = H.s; lo = L.s;
}

__global__ __launch_bounds__(NTHREADS, 2)
void colbert_m32_kernel(const float* __restrict__ qg,
                        const float* __restrict__ pg,
                        const float* __restrict__ ng,
                        double* __restrict__ sum_ws) {
    __shared__ short Bs[2][2][TN * BSTR];   // [buf][hi/lo][doc*BSTR + dim] 34816 B
    __shared__ float part[4];

    const int tid  = threadIdx.x;
    const int w    = tid >> 6;              // wave -> q rows w*64 .. +63
    const int lane = tid & 63;
    const int l32  = lane & 31;
    const int half = lane >> 5;
    const int b    = blockIdx.x;
    const int pass = blockIdx.y;            // 0 -> p (+), 1 -> n (-)

    const float* docb = (pass ? ng : pg) + (size_t)b * Kn * Dn;
    const int   d4    = tid & 31;           // doc-dim chunk this thread stages

    // Prefetch tile 0 (loads in flight during the A-conversion VALU burst).
    float4 pre[4];
    {
        const float4* s4 = (const float4*)docb;
#pragma unroll
        for (int k = 0; k < 4; ++k) pre[k] = s4[tid + 256 * k];
    }

    // A fragments: 64 q-rows per wave, hi/lo bf16 (128 VGPR).
    // 32x32x16 A layout: lane holds A[m = l32][k = half*8 + j], j=0..7.
    short8 Ahi[MI][8], Alo[MI][8];          // [mi][ks], ks = K-slice of 16
    {
        const float* qb = qg + (size_t)b * Qn * Dn;
#pragma unroll
        for (int mi = 0; mi < MI; ++mi)
#pragma unroll
            for (int ks = 0; ks < 8; ++ks)
                cvt8(qb + (size_t)(w * 64 + mi * 32 + l32) * Dn + ks * 16 + half * 8,
                     Ahi[mi][ks], Alo[mi][ks]);
    }

    float maxv[MI][16];                     // running row-max, C/D layout
#pragma unroll
    for (int mi = 0; mi < MI; ++mi)
#pragma unroll
        for (int r = 0; r < 16; ++r) maxv[mi][r] = -3e38f;

    int buf = 0;
    for (int t = 0; t < NT; ++t) {
        // stage tile t -> LDS[buf] (hi & lo planes)
#pragma unroll
        for (int k = 0; k < 4; ++k) {
            int doc = (tid + 256 * k) >> 5;
            stage_chunk(&Bs[buf][0][0], &Bs[buf][1][0], doc, d4, pre[k]);
        }
        __syncthreads();

        // prefetch tile t+1 while MFMAs run
        if (t + 1 < NT) {
            const float4* s4 = (const float4*)(docb + (size_t)(t + 1) * TN * Dn);
#pragma unroll
            for (int k = 0; k < 4; ++k) pre[k] = s4[tid + 256 * k];
        }

        // 32 docs x 64 q-rows, K=128: acc[mi] chained over 8 K-slices x 3 terms
        f32x16 acc[MI];
#pragma unroll
        for (int mi = 0; mi < MI; ++mi)
#pragma unroll
            for (int r = 0; r < 16; ++r) acc[mi][r] = 0.f;

#pragma unroll
        for (int ks = 0; ks < 8; ++ks) {
            const int off = l32 * BSTR + ks * 16 + half * 8;
            short8 bhi = *(const short8*)&Bs[buf][0][off];
            short8 blo = *(const short8*)&Bs[buf][1][off];
#pragma unroll
            for (int mi = 0; mi < MI; ++mi) {
                acc[mi] = __builtin_amdgcn_mfma_f32_32x32x16_bf16(
                    Ahi[mi][ks], bhi, acc[mi], 0, 0, 0);
                acc[mi] = __builtin_amdgcn_mfma_f32_32x32x16_bf16(
                    Alo[mi][ks], bhi, acc[mi], 0, 0, 0);
                acc[mi] = __builtin_amdgcn_mfma_f32_32x32x16_bf16(
                    Ahi[mi][ks], blo, acc[mi], 0, 0, 0);
            }
        }

        // C/D: col(doc) = l32, row = (r&3) + 8*(r>>2) + 4*half
#pragma unroll
        for (int mi = 0; mi < MI; ++mi)
#pragma unroll
            for (int r = 0; r < 16; ++r)
                maxv[mi][r] = fmaxf(maxv[mi][r], acc[mi][r]);
        buf ^= 1;
    }

    // max over the 32 doc-column lanes (within each half)
#pragma unroll
    for (int off = 1; off < 32; off <<= 1)
#pragma unroll
        for (int mi = 0; mi < MI; ++mi)
#pragma unroll
            for (int r = 0; r < 16; ++r)
                maxv[mi][r] = fmaxf(maxv[mi][r], __shfl_xor(maxv[mi][r], off));

    // Each half covers a disjoint set of 16 rows per mi -> sum both halves.
    float s = 0.f;
#pragma unroll
    for (int mi = 0; mi < MI; ++mi)
#pragma unroll
        for (int r = 0; r < 16; ++r) s += maxv[mi][r];
    if (l32 != 0) s = 0.f;                  // one copy per half
    s += __shfl_xor(s, 32);                 // lane 0: half0 + half1
    if (lane == 0) part[w] = s;
    __syncthreads();
    if (tid == 0) {
        double t = (double)part[0] + part[1] + part[2] + part[3];
        atomicAdd(sum_ws, pass ? -t : t);   // S = pos - neg, exact in fp64
    }
}

__global__ void finalize_kernel(const double* __restrict__ sum_ws,
                                float* __restrict__ out) {
    out[0] = fmaxf(0.0f, MARGIN - (float)sum_ws[0]);
}

extern "C" void kernel_launch(void* const* d_in, const int* in_sizes, int n_in,
                              void* d_out, int out_size, void* d_ws, size_t ws_size,
                              hipStream_t stream) {
    const float* q = (const float*)d_in[0];
    const float* p = (const float*)d_in[1];
    const float* n = (const float*)d_in[2];
    float* out = (float*)d_out;
    double* ws = (double*)d_ws;

    hipMemsetAsync(ws, 0, sizeof(double), stream);  // ws re-poisoned each call

    colbert_m32_kernel<<<dim3(Bn, 2), NTHREADS, 0, stream>>>(q, p, n, ws);
    finalize_kernel<<<1, 1, 0, stream>>>(ws, out);
}